// Round 12
// baseline (133.693 us; speedup 1.0000x reference)
//
#include <hip/hip_runtime.h>
#include <stdint.h>

#define NROW 8192
#define DIM  512
#define NOUT 16
#define GAMMA 0.001f
// exp(2*gamma*c) = exp2(c * 2*gamma*log2(e))
#define EXP2S (2.0f * GAMMA * 1.44269504088896340736f)
#define SC1 0x7F7F7F7F   // e8m0 scale bytes = 127 -> 2^0 = 1.0 (unit scale)

typedef __bf16 bf16_t;
typedef bf16_t bf16x4_t __attribute__((ext_vector_type(4)));
typedef bf16_t bf16x8_t __attribute__((ext_vector_type(8)));
typedef float  floatx4_t  __attribute__((ext_vector_type(4)));
typedef float  floatx16_t __attribute__((ext_vector_type(16)));
typedef int    intx4_t  __attribute__((ext_vector_type(4)));
typedef int    intx8_t  __attribute__((ext_vector_type(8)));

// two coalesced dwordx4 -> one 32B MFMA operand
__device__ __forceinline__ intx8_t ld_frag(const uint8_t* p) {
    const intx4_t lo = *(const intx4_t*)(p);
    const intx4_t hi = *(const intx4_t*)(p + 16);
    return __builtin_shufflevector(lo, hi, 0, 1, 2, 3, 4, 5, 6, 7);
}

// ---------- prep: fp32 -> fp8 e4m3 in MFMA-packed layout + norms + alpha' ----
// Packed layout: for 32-row tile b, 64-k step s, flat[(b*8+s)*2048 + L*32 + j]
// holds row b*32+(L&31), k = s*64 + (L>>5)*32 + j  == lane L's operand bytes of
// mfma_scale_32x32x64_f8f6f4. A frag load from global is then two coalesced
// dwordx4 (lane*32, +16) -- no LDS staging needed at all.
__global__ __launch_bounds__(256) void prep_convert(
    const float* __restrict__ X, const float* __restrict__ T,
    const float* __restrict__ alpha,
    uint8_t* __restrict__ X2, uint8_t* __restrict__ T2,
    float* __restrict__ xfac, bf16_t* __restrict__ alphaTp)
{
    const int w = threadIdx.x >> 6, lane = threadIdx.x & 63;
    const int row = blockIdx.x * 4 + w;              // 0..16383
    const bool is_test = row < NROW;
    const float* src = is_test ? X : T;
    uint8_t* dst = is_test ? X2 : T2;
    const int r = is_test ? row : row - NROW;
    // lane owns floats [lane*8, lane*8+8) -> one 8-byte fp8 chunk
    const float4* s4 = (const float4*)(src + (size_t)r * DIM);
    const float4 v0 = s4[lane * 2];
    const float4 v1 = s4[lane * 2 + 1];
    float ss = v0.x*v0.x + v0.y*v0.y + v0.z*v0.z + v0.w*v0.w
             + v1.x*v1.x + v1.y*v1.y + v1.z*v1.z + v1.w*v1.w;
    int lo = __builtin_amdgcn_cvt_pk_fp8_f32(v0.x, v0.y, 0, false);
    lo     = __builtin_amdgcn_cvt_pk_fp8_f32(v0.z, v0.w, lo, true);
    int hi = __builtin_amdgcn_cvt_pk_fp8_f32(v1.x, v1.y, 0, false);
    hi     = __builtin_amdgcn_cvt_pk_fp8_f32(v1.z, v1.w, hi, true);
    const int k0 = lane * 8;                         // 8 bytes, within one 32-k block
    const size_t off = ((size_t)((r >> 5) * 8 + (k0 >> 6)) << 11)
                     + (size_t)(((((k0 >> 5) & 1) << 5) | (r & 31)) * 32 + (k0 & 31));
    *(int2*)(dst + off) = make_int2(lo, hi);
#pragma unroll
    for (int m = 32; m > 0; m >>= 1) ss += __shfl_xor(ss, m, 64);
    const float f = __expf(-GAMMA * ss);             // all lanes hold the sum
    if (is_test) {
        if (lane == 0) xfac[r] = f;
    } else if (lane < 16) {
        // alphaT'[o][j] = exp(-g*||y_j||^2) * alpha[j][o]
        alphaTp[(size_t)lane * NROW + r] = (bf16_t)(alpha[r * 16 + lane] * f);
    }
}

// ---------- main: barrier-free K-loop, packed-global frags, 32x32x64 MX fp8 --
// r10's wall was the LDS read pipe (~41us of ds_read_b128 time/CU) -- not MFMA
// (14.4us). Operand frags now load straight from the packed global layout
// (coalesced dwordx4, L1/L2-resident), LDS holds ONLY the wave-private K''
// epilogue tile. Zero __syncthreads in the K/t loops -> no vmcnt(0) barrier
// drains; compiler emits fine-grained vmcnt for the register prefetch.
#define TPT 4        // train tiles per block (16 chunks x 4 tiles = 8192)
#define KLD2 72      // padded row stride (bf16) of per-wave K'' tile

__global__ __launch_bounds__(256, 2) void rbf_main(
    const uint8_t* __restrict__ X2, const uint8_t* __restrict__ T2,
    const bf16_t* __restrict__ alphaTp, const float* __restrict__ xfac,
    float* __restrict__ out)
{
    // kw only: 4 waves x [test 64][train 72] bf16 = 36864 B (stash unions)
    __shared__ __align__(16) unsigned char smem[4 * 64 * KLD2 * 2];

    const int tid = threadIdx.x;
    const int w = tid >> 6, lane = tid & 63;
    const int wm = w >> 1, wn = w & 1;               // train half / test half
    const int quad = lane >> 4, l15 = lane & 15;
    const int l31 = lane & 31, lk = lane >> 5;

    const int rb = blockIdx.x;                       // 0..63  test block (XCD = rb%8)
    const int chunk = blockIdx.y;                    // 0..15  train chunk
    const int row0 = rb * 128;
    const int cb0 = chunk * (TPT * 128);

    // persistent X (B-operand) frag pointers: tile b = rb*4 + wn*2 + ni
    const uint8_t* xp0 = X2 + (((size_t)(rb * 4 + wn * 2) * 8) << 11) + lane * 32;
    const uint8_t* xp1 = xp0 + (8 << 11);

    const floatx4_t vzero = {0.f, 0.f, 0.f, 0.f};
    floatx4_t oacc[4];
#pragma unroll
    for (int i = 0; i < 4; ++i) oacc[i] = vzero;

    bf16_t* kw = (bf16_t*)smem + w * (64 * KLD2);    // wave-private K'' region

    for (int t = 0; t < TPT; ++t) {
        const int cb = cb0 + t * 128;
        // T (A-operand) tile pointers: tile b = chunk*16 + t*4 + wm*2 + mi
        const uint8_t* tp0 = T2 + (((size_t)(chunk * 16 + t * 4 + wm * 2) * 8) << 11)
                             + lane * 32;
        const uint8_t* tp1 = tp0 + (8 << 11);

        floatx16_t acc[2][2];
#pragma unroll
        for (int i = 0; i < 2; ++i)
#pragma unroll
            for (int j = 0; j < 2; ++j)
#pragma unroll
                for (int e = 0; e < 16; ++e) acc[i][j][e] = 0.f;

        // 1-deep register prefetch pipeline over the 8 64-k steps
        intx8_t ca0 = ld_frag(tp0), ca1 = ld_frag(tp1);
        intx8_t cb0v = ld_frag(xp0), cb1v = ld_frag(xp1);
#pragma unroll
        for (int s = 0; s < 8; ++s) {
            intx8_t na0, na1, nb0, nb1;
            if (s < 7) {
                na0 = ld_frag(tp0 + (s + 1) * 2048);
                na1 = ld_frag(tp1 + (s + 1) * 2048);
                nb0 = ld_frag(xp0 + (s + 1) * 2048);
                nb1 = ld_frag(xp1 + (s + 1) * 2048);
            }
            acc[0][0] = __builtin_amdgcn_mfma_scale_f32_32x32x64_f8f6f4(
                ca0, cb0v, acc[0][0], 0, 0, 0, SC1, 0, SC1);
            acc[0][1] = __builtin_amdgcn_mfma_scale_f32_32x32x64_f8f6f4(
                ca0, cb1v, acc[0][1], 0, 0, 0, SC1, 0, SC1);
            acc[1][0] = __builtin_amdgcn_mfma_scale_f32_32x32x64_f8f6f4(
                ca1, cb0v, acc[1][0], 0, 0, 0, SC1, 0, SC1);
            acc[1][1] = __builtin_amdgcn_mfma_scale_f32_32x32x64_f8f6f4(
                ca1, cb1v, acc[1][1], 0, 0, 0, SC1, 0, SC1);
            if (s < 7) { ca0 = na0; ca1 = na1; cb0v = nb0; cb1v = nb1; }
        }

        // K'' = exp(2*gamma*cross) -> bf16 into wave-private kw[test][train].
        // 32x32 C-layout: acc[mi][ni] reg r -> train = mi*32+(r&3)+8*(r>>2)+4*lk,
        // test = ni*32 + l31. Regs 4g..4g+3 are 4 consecutive train rows -> 8B st.
#pragma unroll
        for (int ni = 0; ni < 2; ++ni)
#pragma unroll
            for (int mi = 0; mi < 2; ++mi)
#pragma unroll
                for (int rg = 0; rg < 4; ++rg) {
                    bf16x4_t pk;
#pragma unroll
                    for (int j = 0; j < 4; ++j)
                        pk[j] = (bf16_t)__builtin_amdgcn_exp2f(acc[mi][ni][rg * 4 + j] * EXP2S);
                    *(bf16x4_t*)(kw + (ni * 32 + l31) * KLD2
                                 + mi * 32 + rg * 8 + lk * 4) = pk;
                }
        // no barrier: kw is wave-private; in-wave lgkmcnt orders write->read

        // epilogue: oacc[n4] += K''[test 16(n4) x train 64] @ alpha'[64 x 16]
#pragma unroll
        for (int ks = 0; ks < 2; ++ks) {
            const bf16x8_t bv = *(const bf16x8_t*)(alphaTp + (size_t)l15 * NROW
                                                   + cb + wm * 64 + ks * 32 + quad * 8);
#pragma unroll
            for (int n4 = 0; n4 < 4; ++n4) {
                const bf16x8_t av = *(const bf16x8_t*)(kw + (n4 * 16 + l15) * KLD2
                                                       + ks * 32 + quad * 8);
                oacc[n4] = __builtin_amdgcn_mfma_f32_16x16x32_bf16(av, bv, oacc[n4], 0, 0, 0);
            }
        }
    }

    // reduce the two train halves (wm=0,1) through LDS, then atomicAdd to out
    __syncthreads();
    float* stash = (float*)smem;
    if (wm == 1) {
#pragma unroll
        for (int ni = 0; ni < 4; ++ni)
            *(floatx4_t*)(stash + wn * 1024 + ni * 256 + lane * 4) = oacc[ni];
    }
    __syncthreads();
    if (wm == 0) {
#pragma unroll
        for (int ni = 0; ni < 4; ++ni) {
            const floatx4_t o2 = *(const floatx4_t*)(stash + wn * 1024 + ni * 256 + lane * 4);
            const int trow = row0 + wn * 64 + ni * 16 + quad * 4;
            const float4 xf = *(const float4*)(xfac + trow);
            atomicAdd(out + (size_t)(trow + 0) * NOUT + l15, (oacc[ni][0] + o2[0]) * xf.x);
            atomicAdd(out + (size_t)(trow + 1) * NOUT + l15, (oacc[ni][1] + o2[1]) * xf.y);
            atomicAdd(out + (size_t)(trow + 2) * NOUT + l15, (oacc[ni][2] + o2[2]) * xf.z);
            atomicAdd(out + (size_t)(trow + 3) * NOUT + l15, (oacc[ni][3] + o2[3]) * xf.w);
        }
    }
}

extern "C" void kernel_launch(void* const* d_in, const int* in_sizes, int n_in,
                              void* d_out, int out_size, void* d_ws, size_t ws_size,
                              hipStream_t stream) {
    (void)in_sizes; (void)n_in; (void)out_size; (void)ws_size;
    const float* X     = (const float*)d_in[0];
    const float* T     = (const float*)d_in[1];
    const float* alpha = (const float*)d_in[2];

    char* ws = (char*)d_ws;
    uint8_t* X2     = (uint8_t*)ws;                                  // 4 MB packed
    uint8_t* T2     = (uint8_t*)(ws + (8u << 20));                   // 4 MB packed
    float*   xfac   = (float*)(ws + (16u << 20));                    // 32 KB
    bf16_t*  alphaTp= (bf16_t*)(ws + (16u << 20) + (64u << 10));     // 256 KB
    float*   out    = (float*)d_out;

    hipMemsetAsync(out, 0, (size_t)NROW * NOUT * sizeof(float), stream);
    prep_convert<<<4096, 256, 0, stream>>>(X, T, alpha, X2, T2, xfac, alphaTp);
    dim3 grid(64, 16);   // x = rb (XCD affinity for X), y = chunk
    rbf_main<<<grid, 256, 0, stream>>>(X2, T2, alphaTp, xfac, out);
}